// Round 12
// baseline (337.269 us; speedup 1.0000x reference)
//
#include <hip/hip_runtime.h>
#include <math.h>

#define HID 64
#define BSH 8                      // 256 nodes per bucket
#define BN 256
#define SRCBITS 17
#define SRCMASK ((1 << SRCBITS) - 1)
#define PB 512                     // partition chunks
#define MAXNB 512                  // max buckets (n <= 131072)
#define ELLW 96
#define ROWB 7                     // log2 bytes per bf16 row (64*2)

typedef unsigned short bfraw;      // raw bf16 storage
typedef float f32x2 __attribute__((ext_vector_type(2)));
typedef __bf16 bf16x2_t __attribute__((ext_vector_type(2)));

__device__ __forceinline__ float bf_lo(unsigned u) { return __uint_as_float(u << 16); }
__device__ __forceinline__ float bf_hi(unsigned u) { return __uint_as_float(u & 0xffff0000u); }
__device__ __forceinline__ unsigned short f2bf(float f) {
    unsigned u = __float_as_uint(f);
    u += 0x7fffu + ((u >> 16) & 1u);   // round-to-nearest-even (finite values)
    return (unsigned short)(u >> 16);
}
__device__ __forceinline__ unsigned pack2(float a, float b) {
    return (unsigned)f2bf(a) | ((unsigned)f2bf(b) << 16);
}
// packed bf16 pair -> f32 pair
__device__ __forceinline__ f32x2 bf2f2(unsigned u) {
#if __has_builtin(__builtin_amdgcn_cvt_scalef32_pk_f32_bf16)
    return __builtin_amdgcn_cvt_scalef32_pk_f32_bf16(__builtin_bit_cast(bf16x2_t, u), 1.0f);
#else
    f32x2 r;
    r.x = bf_lo(u);
    r.y = bf_hi(u);
    return r;
#endif
}

// acc[c] += sum_j xv[j] * wj[c]
__device__ __forceinline__ void fma4x4(float4& acc, const float4 xv,
                                       const float4 w0, const float4 w1,
                                       const float4 w2, const float4 w3) {
    acc.x = fmaf(xv.x, w0.x, acc.x); acc.y = fmaf(xv.x, w0.y, acc.y);
    acc.z = fmaf(xv.x, w0.z, acc.z); acc.w = fmaf(xv.x, w0.w, acc.w);
    acc.x = fmaf(xv.y, w1.x, acc.x); acc.y = fmaf(xv.y, w1.y, acc.y);
    acc.z = fmaf(xv.y, w1.z, acc.z); acc.w = fmaf(xv.y, w1.w, acc.w);
    acc.x = fmaf(xv.z, w2.x, acc.x); acc.y = fmaf(xv.z, w2.y, acc.y);
    acc.z = fmaf(xv.z, w2.z, acc.z); acc.w = fmaf(xv.z, w2.w, acc.w);
    acc.x = fmaf(xv.w, w3.x, acc.x); acc.y = fmaf(xv.w, w3.y, acc.y);
    acc.z = fmaf(xv.w, w3.z, acc.z); acc.w = fmaf(xv.w, w3.w, acc.w);
}

// ================= small utility =================
__global__ void k_zero_int(int* __restrict__ p, int n) {
    int i = blockIdx.x * blockDim.x + threadIdx.x;
    if (i < n) p[i] = 0;
}

__global__ void k_zero_padrow(bfraw* __restrict__ a, bfraw* __restrict__ b, long off) {
    int t = threadIdx.x;
    if (t < HID) { a[off + t] = 0; b[off + t] = 0; }
}

// ================= P1: per-chunk bucket histogram =================
__global__ void k_hist(const int* __restrict__ dst, int* __restrict__ table,
                       int E, int nb, int chunk) {
    __shared__ int lh[MAXNB];
    for (int t = threadIdx.x; t < nb; t += 256) lh[t] = 0;
    __syncthreads();
    int beg = blockIdx.x * chunk;
    int end = beg + chunk; if (end > E) end = E;
    for (int e = beg + threadIdx.x; e < end; e += 256)
        atomicAdd(&lh[dst[e] >> BSH], 1);
    __syncthreads();
    for (int t = threadIdx.x; t < nb; t += 256)
        table[t * PB + blockIdx.x] = lh[t];
}

// ================= P2a: per-bucket exclusive scan across chunks =================
__global__ void k_scanA(int* __restrict__ table, int* __restrict__ rowsum) {
    __shared__ int lds[PB];
    const int bu = blockIdx.x;
    const int t = threadIdx.x;
    int v = table[bu * PB + t];
    lds[t] = v;
    __syncthreads();
    for (int off = 1; off < PB; off <<= 1) {
        int u = (t >= off) ? lds[t - off] : 0;
        __syncthreads();
        lds[t] += u;
        __syncthreads();
    }
    table[bu * PB + t] = lds[t] - v;
    if (t == PB - 1) rowsum[bu] = lds[t];
}

// ================= P2b: exclusive scan of bucket totals =================
__global__ void k_scanB(int* __restrict__ rowsum, int nb) {
    __shared__ int lds[PB];
    const int t = threadIdx.x;
    int v = (t < nb) ? rowsum[t] : 0;
    lds[t] = v;
    __syncthreads();
    for (int off = 1; off < PB; off <<= 1) {
        int u = (t >= off) ? lds[t - off] : 0;
        __syncthreads();
        lds[t] += u;
        __syncthreads();
    }
    if (t < nb) rowsum[t] = lds[t] - v;
}

// ================= P3: partition scatter (bucket base folded in) =================
__global__ void k_pscatter(const int* __restrict__ src, const int* __restrict__ dst,
                           const int* __restrict__ excl, const int* __restrict__ rowsum,
                           int* __restrict__ part, int E, int nb, int chunk) {
    __shared__ int cur[MAXNB];
    for (int t = threadIdx.x; t < nb; t += 256)
        cur[t] = excl[t * PB + blockIdx.x] + rowsum[t];
    __syncthreads();
    int beg = blockIdx.x * chunk;
    int end = beg + chunk; if (end > E) end = E;
    for (int e = beg + threadIdx.x; e < end; e += 256) {
        int d = dst[e];
        int bu = d >> BSH;
        int pos = atomicAdd(&cur[bu], 1);
        part[pos] = ((d & (BN - 1)) << SRCBITS) | src[e];
    }
}

// ================= P4: per-bucket ELL fill (BYTE offsets) + degree + dinv + pad-to-8 ==========
__global__ void k_bell(const int* __restrict__ part, const int* __restrict__ excl,
                       const int* __restrict__ rowsum,
                       int* __restrict__ ell, int* __restrict__ deg,
                       float* __restrict__ dinv, int E, int nb, int n) {
    __shared__ int cnt[BN];
    int b = blockIdx.x;
    for (int t = threadIdx.x; t < BN; t += 256) cnt[t] = 0;
    __syncthreads();
    int beg = excl[b * PB] + rowsum[b];
    int end = (b == nb - 1) ? E : excl[(b + 1) * PB] + rowsum[b + 1];
    for (int i = beg + threadIdx.x; i < end; i += 256) {
        int c = part[i];
        int dl = c >> SRCBITS;
        int p = atomicAdd(&cnt[dl], 1);
        if (p < ELLW) ell[(size_t)((b << BSH) + dl) * ELLW + p] = (c & SRCMASK) << ROWB;
    }
    __syncthreads();
    for (int t = threadIdx.x; t < BN; t += 256) {
        int node = (b << BSH) + t;
        if (node < n) {
            int dgv = cnt[t];
            int len = dgv < ELLW ? dgv : ELLW;
            int len8 = (len + 7) & ~7;      // ELLW%8==0 so len8<=ELLW
            int* r = ell + (size_t)node * ELLW;
            for (int p = len; p < len8; ++p) r[p] = n << ROWB;   // pad -> zero row
            deg[node] = dgv;
            dinv[node] = rsqrtf((float)(dgv + 1));
        }
    }
}

// ================= GEMM + dinv scale -> bf16 (b128 W reads, 4-row x 4-ch register tile) ========
template<int K>
__launch_bounds__(256)
__global__ void k_gemm_bf(const float* __restrict__ x, const float* __restrict__ W,
                          const float* __restrict__ dinv, bfraw* __restrict__ g, int n) {
    __shared__ float sW[K * HID];
    for (int t = threadIdx.x; t < K * HID / 4; t += 256)
        ((float4*)sW)[t] = ((const float4*)W)[t];
    __syncthreads();
    const int wv = threadIdx.x >> 6;
    const int lane = threadIdx.x & 63;
    const int cq = lane & 15;
    const int rq = lane >> 4;
    const int base = blockIdx.x * 64 + wv * 16 + rq * 4;
    if (base >= n) return;
    if (base + 3 < n) {
        const float* xr = x + (size_t)base * K;
        float4 a0 = {0,0,0,0}, a1 = {0,0,0,0}, a2 = {0,0,0,0}, a3 = {0,0,0,0};
#pragma unroll 2
        for (int k = 0; k < K; k += 4) {
            float4 x0 = *(const float4*)(xr + k);
            float4 x1 = *(const float4*)(xr + K + k);
            float4 x2 = *(const float4*)(xr + 2 * K + k);
            float4 x3 = *(const float4*)(xr + 3 * K + k);
            const float* wp = sW + k * HID + cq * 4;
            float4 w0 = *(const float4*)(wp);
            float4 w1 = *(const float4*)(wp + HID);
            float4 w2 = *(const float4*)(wp + 2 * HID);
            float4 w3 = *(const float4*)(wp + 3 * HID);
            fma4x4(a0, x0, w0, w1, w2, w3);
            fma4x4(a1, x1, w0, w1, w2, w3);
            fma4x4(a2, x2, w0, w1, w2, w3);
            fma4x4(a3, x3, w0, w1, w2, w3);
        }
        float d0 = dinv[base], d1 = dinv[base + 1], d2 = dinv[base + 2], d3 = dinv[base + 3];
        uint2 o;
        o.x = pack2(a0.x * d0, a0.y * d0); o.y = pack2(a0.z * d0, a0.w * d0);
        *(uint2*)(g + (size_t)(base + 0) * HID + cq * 4) = o;
        o.x = pack2(a1.x * d1, a1.y * d1); o.y = pack2(a1.z * d1, a1.w * d1);
        *(uint2*)(g + (size_t)(base + 1) * HID + cq * 4) = o;
        o.x = pack2(a2.x * d2, a2.y * d2); o.y = pack2(a2.z * d2, a2.w * d2);
        *(uint2*)(g + (size_t)(base + 2) * HID + cq * 4) = o;
        o.x = pack2(a3.x * d3, a3.y * d3); o.y = pack2(a3.z * d3, a3.w * d3);
        *(uint2*)(g + (size_t)(base + 3) * HID + cq * 4) = o;
    } else {
        for (int r = 0; r < 4; ++r) {
            int row = base + r;
            if (row >= n) break;
            const float* xp = x + (size_t)row * K;
            float4 acc = {0,0,0,0};
            for (int k = 0; k < K; k += 4) {
                float4 xv = *(const float4*)(xp + k);
                const float* wp = sW + k * HID + cq * 4;
                float4 w0 = *(const float4*)(wp);
                float4 w1 = *(const float4*)(wp + HID);
                float4 w2 = *(const float4*)(wp + 2 * HID);
                float4 w3 = *(const float4*)(wp + 3 * HID);
                fma4x4(acc, xv, w0, w1, w2, w3);
            }
            float di = dinv[row];
            uint2 o;
            o.x = pack2(acc.x * di, acc.y * di); o.y = pack2(acc.z * di, acc.w * di);
            *(uint2*)(g + (size_t)row * HID + cq * 4) = o;
        }
    }
}

// ================= bf16 aggregation v5: 2 nodes/wave, 8 loads in flight per lane ==============
// lane bits: [5]=node half, [4:3]=edge group (4/node), [2:0]=channel octet.
template<bool FUSE>
__launch_bounds__(256)
__global__ void k_aggb(const int* __restrict__ deg, const int* __restrict__ ell,
                       const bfraw* __restrict__ g, const float* __restrict__ dinv,
                       const float* __restrict__ bias, const float* __restrict__ Wn,
                       bfraw* __restrict__ outp, int n) {
    __shared__ __align__(16) float sW[FUSE ? HID * HID : 4];
    __shared__ __align__(16) float sH[8][HID];
    if (FUSE) {
        for (int t = threadIdx.x; t < HID * HID / 4; t += 256)
            ((float4*)sW)[t] = ((const float4*)Wn)[t];
    }
    const int wv = threadIdx.x >> 6;
    const int lane = threadIdx.x & 63;
    const int half = lane >> 5;
    const int grp4 = (lane >> 3) & 3;
    const int cq = lane & 7;
    const int cqb = cq * 16;             // byte offset within row
    const int nodeSlot = wv * 2 + half;
    const int node = blockIdx.x * 8 + nodeSlot;
    const char* gb = (const char*)g;
    f32x2 a01 = {0, 0}, a23 = {0, 0}, a45 = {0, 0}, a67 = {0, 0};
    if (node < n) {
        int dg = deg[node];
        int len = dg < ELLW ? dg : ELLW;
        int len8 = (len + 7) & ~7;
        const int* row = ell + (size_t)node * ELLW;
        int j = grp4;
        // 8-deep stage: 8 gathers in flight per lane
        for (; j + 28 < len8; j += 32) {
            int o0 = row[j],      o1 = row[j + 4],  o2 = row[j + 8],  o3 = row[j + 12];
            int o4 = row[j + 16], o5 = row[j + 20], o6 = row[j + 24], o7 = row[j + 28];
            const uint4 v0 = *(const uint4*)(gb + o0 + cqb);
            const uint4 v1 = *(const uint4*)(gb + o1 + cqb);
            const uint4 v2 = *(const uint4*)(gb + o2 + cqb);
            const uint4 v3 = *(const uint4*)(gb + o3 + cqb);
            const uint4 v4 = *(const uint4*)(gb + o4 + cqb);
            const uint4 v5 = *(const uint4*)(gb + o5 + cqb);
            const uint4 v6 = *(const uint4*)(gb + o6 + cqb);
            const uint4 v7 = *(const uint4*)(gb + o7 + cqb);
            a01 += ((bf2f2(v0.x) + bf2f2(v1.x)) + (bf2f2(v2.x) + bf2f2(v3.x)))
                 + ((bf2f2(v4.x) + bf2f2(v5.x)) + (bf2f2(v6.x) + bf2f2(v7.x)));
            a23 += ((bf2f2(v0.y) + bf2f2(v1.y)) + (bf2f2(v2.y) + bf2f2(v3.y)))
                 + ((bf2f2(v4.y) + bf2f2(v5.y)) + (bf2f2(v6.y) + bf2f2(v7.y)));
            a45 += ((bf2f2(v0.z) + bf2f2(v1.z)) + (bf2f2(v2.z) + bf2f2(v3.z)))
                 + ((bf2f2(v4.z) + bf2f2(v5.z)) + (bf2f2(v6.z) + bf2f2(v7.z)));
            a67 += ((bf2f2(v0.w) + bf2f2(v1.w)) + (bf2f2(v2.w) + bf2f2(v3.w)))
                 + ((bf2f2(v4.w) + bf2f2(v5.w)) + (bf2f2(v6.w) + bf2f2(v7.w)));
        }
        // one 4-deep stage
        if (j + 12 < len8) {
            int o0 = row[j], o1 = row[j + 4], o2 = row[j + 8], o3 = row[j + 12];
            const uint4 v0 = *(const uint4*)(gb + o0 + cqb);
            const uint4 v1 = *(const uint4*)(gb + o1 + cqb);
            const uint4 v2 = *(const uint4*)(gb + o2 + cqb);
            const uint4 v3 = *(const uint4*)(gb + o3 + cqb);
            a01 += (bf2f2(v0.x) + bf2f2(v1.x)) + (bf2f2(v2.x) + bf2f2(v3.x));
            a23 += (bf2f2(v0.y) + bf2f2(v1.y)) + (bf2f2(v2.y) + bf2f2(v3.y));
            a45 += (bf2f2(v0.z) + bf2f2(v1.z)) + (bf2f2(v2.z) + bf2f2(v3.z));
            a67 += (bf2f2(v0.w) + bf2f2(v1.w)) + (bf2f2(v2.w) + bf2f2(v3.w));
            j += 16;
        }
        // <=3 singles
        for (; j < len8; j += 4) {
            int o0 = row[j];
            const uint4 v0 = *(const uint4*)(gb + o0 + cqb);
            a01 += bf2f2(v0.x);
            a23 += bf2f2(v0.y);
            a45 += bf2f2(v0.z);
            a67 += bf2f2(v0.w);
        }
    }
    // reduce across 4 groups within each 32-lane half (bit5 never crossed)
    a01.x += __shfl_xor(a01.x, 8);  a01.y += __shfl_xor(a01.y, 8);
    a23.x += __shfl_xor(a23.x, 8);  a23.y += __shfl_xor(a23.y, 8);
    a45.x += __shfl_xor(a45.x, 8);  a45.y += __shfl_xor(a45.y, 8);
    a67.x += __shfl_xor(a67.x, 8);  a67.y += __shfl_xor(a67.y, 8);
    a01.x += __shfl_xor(a01.x, 16); a01.y += __shfl_xor(a01.y, 16);
    a23.x += __shfl_xor(a23.x, 16); a23.y += __shfl_xor(a23.y, 16);
    a45.x += __shfl_xor(a45.x, 16); a45.y += __shfl_xor(a45.y, 16);
    a67.x += __shfl_xor(a67.x, 16); a67.y += __shfl_xor(a67.y, 16);
    if (node < n && grp4 == 0) {
        const uint4 sv = *(const uint4*)(gb + ((size_t)node << ROWB) + cqb);
        float di = dinv[node];
        const float4 bv0 = *(const float4*)(bias + cq * 8);
        const float4 bv1 = *(const float4*)(bias + cq * 8 + 4);
        f32x2 se0 = bf2f2(sv.x), se1 = bf2f2(sv.y), se2 = bf2f2(sv.z), se3 = bf2f2(sv.w);
        float h0 = di * (a01.x + se0.x) + bv0.x;
        float h1 = di * (a01.y + se0.y) + bv0.y;
        float h2 = di * (a23.x + se1.x) + bv0.z;
        float h3 = di * (a23.y + se1.y) + bv0.w;
        float h4 = di * (a45.x + se2.x) + bv1.x;
        float h5 = di * (a45.y + se2.y) + bv1.y;
        float h6 = di * (a67.x + se3.x) + bv1.z;
        float h7 = di * (a67.y + se3.y) + bv1.w;
        if (!FUSE) {
            uint4 o;
            o.x = pack2(h0, h1); o.y = pack2(h2, h3);
            o.z = pack2(h4, h5); o.w = pack2(h6, h7);
            *(uint4*)(outp + (size_t)node * HID + cq * 8) = o;
        } else {
            h0 = fmaxf(h0, 0.0f); h1 = fmaxf(h1, 0.0f); h2 = fmaxf(h2, 0.0f); h3 = fmaxf(h3, 0.0f);
            h4 = fmaxf(h4, 0.0f); h5 = fmaxf(h5, 0.0f); h6 = fmaxf(h6, 0.0f); h7 = fmaxf(h7, 0.0f);
            *(float4*)(&sH[nodeSlot][cq * 8])     = make_float4(h0, h1, h2, h3);
            *(float4*)(&sH[nodeSlot][cq * 8 + 4]) = make_float4(h4, h5, h6, h7);
        }
    }
    if (FUSE) {
        __syncthreads();   // covers sW staging + sH visibility
        const int c4 = lane & 15;
        const int kh = (lane >> 4) & 1;
        float4 acc = {0, 0, 0, 0};
        if (node < n) {
            const float* hr = sH[nodeSlot];
#pragma unroll
            for (int kk = 0; kk < 32; kk += 4) {
                int k = kh * 32 + kk;
                float4 hv = *(const float4*)(hr + k);
                const float* wp = sW + k * HID + c4 * 4;
                float4 w0 = *(const float4*)(wp);
                float4 w1 = *(const float4*)(wp + HID);
                float4 w2 = *(const float4*)(wp + 2 * HID);
                float4 w3 = *(const float4*)(wp + 3 * HID);
                fma4x4(acc, hv, w0, w1, w2, w3);
            }
        }
        acc.x += __shfl_xor(acc.x, 16); acc.y += __shfl_xor(acc.y, 16);
        acc.z += __shfl_xor(acc.z, 16); acc.w += __shfl_xor(acc.w, 16);
        if (node < n && kh == 0) {
            float di = dinv[node];
            uint2 o;
            o.x = pack2(acc.x * di, acc.y * di);
            o.y = pack2(acc.z * di, acc.w * di);
            *(uint2*)(outp + (size_t)node * HID + c4 * 4) = o;
        }
    }
}

// ================= link scores from bf16 h3: 8 lanes/edge =================
__launch_bounds__(256)
__global__ void k_score_bf(const int* __restrict__ ls, const int* __restrict__ ld,
                           const bfraw* __restrict__ h, float* __restrict__ out, int EL) {
    const int wv = threadIdx.x >> 6;
    const int lane = threadIdx.x & 63;
    const int grp = lane >> 3;
    const int cq = lane & 7;
    long e = (long)blockIdx.x * 32 + wv * 8 + grp;
    if (e >= EL) return;   // group-uniform
    int s = ls[e];
    int d = ld[e];
    const uint4 va = *(const uint4*)(h + (size_t)s * HID + cq * 8);
    const uint4 vb = *(const uint4*)(h + (size_t)d * HID + cq * 8);
    f32x2 a0 = bf2f2(va.x), b0 = bf2f2(vb.x);
    f32x2 a1 = bf2f2(va.y), b1 = bf2f2(vb.y);
    f32x2 a2 = bf2f2(va.z), b2 = bf2f2(vb.z);
    f32x2 a3 = bf2f2(va.w), b3 = bf2f2(vb.w);
    float p = a0.x * b0.x + a0.y * b0.y + a1.x * b1.x + a1.y * b1.y
            + a2.x * b2.x + a2.y * b2.y + a3.x * b3.x + a3.y * b3.y;
    p += __shfl_xor(p, 1);
    p += __shfl_xor(p, 2);
    p += __shfl_xor(p, 4);
    if (cq == 0) out[e] = 1.0f / (1.0f + __expf(-p));
}

// ================= fallback: proven r3 fp32 kernels (index-based ELL) =================
__global__ void k_ell_fill(const int* __restrict__ src, const int* __restrict__ dst,
                           int* __restrict__ cur, int* __restrict__ ell, int E) {
    int e = blockIdx.x * blockDim.x + threadIdx.x;
    if (e < E) {
        int d = dst[e];
        int p = atomicAdd(&cur[d], 1);
        if (p < ELLW) ell[(size_t)d * ELLW + p] = src[e];
    }
}
__global__ void k_dinv_from_deg(const int* __restrict__ deg, float* __restrict__ dinv, int n) {
    int i = blockIdx.x * blockDim.x + threadIdx.x;
    if (i < n) dinv[i] = rsqrtf((float)(deg[i] + 1));
}
template<int K>
__launch_bounds__(256)
__global__ void k_gemm_f32(const float* __restrict__ x, const float* __restrict__ W,
                           const float* __restrict__ dinv, float* __restrict__ g, int n) {
    __shared__ float sW[K * HID];
    for (int t = threadIdx.x; t < K * HID; t += 256) sW[t] = W[t];
    __syncthreads();
    const int lane = threadIdx.x & 63;
    const int rowInBlk = threadIdx.x >> 6;
    const int ROWS = 32;
    const int base = blockIdx.x * ROWS;
    for (int r = rowInBlk; r < ROWS; r += 4) {
        int i = base + r;
        if (i >= n) return;
        const float* xr = x + (size_t)i * K;
        float acc = 0.0f;
#pragma unroll
        for (int k = 0; k < K; k += 4) {
            float4 xv = *(const float4*)(xr + k);
            acc = fmaf(xv.x, sW[(k + 0) * HID + lane], acc);
            acc = fmaf(xv.y, sW[(k + 1) * HID + lane], acc);
            acc = fmaf(xv.z, sW[(k + 2) * HID + lane], acc);
            acc = fmaf(xv.w, sW[(k + 3) * HID + lane], acc);
        }
        g[(size_t)i * HID + lane] = acc * dinv[i];
    }
}
__launch_bounds__(256)
__global__ void k_agg_gemm(const int* __restrict__ deg, const int* __restrict__ ell,
                           const float* __restrict__ g, const float* __restrict__ dinv,
                           const float* __restrict__ bias, const float* __restrict__ Wn,
                           float* __restrict__ gout, int n) {
    __shared__ float sW[HID * HID];
    __shared__ float sH[4][HID];
    for (int t = threadIdx.x; t < HID * HID; t += 256) sW[t] = Wn[t];
    const int wv = threadIdx.x >> 6;
    const int lane = threadIdx.x & 63;
    const int node = blockIdx.x * 4 + wv;
    if (node < n) {
        int dg = deg[node];
        int len = dg < ELLW ? dg : ELLW;
        const int* row = ell + (size_t)node * ELLW;
        float acc = g[(size_t)node * HID + lane];
        int j = 0;
        for (; j + 4 <= len; j += 4) {
            int s0 = row[j], s1 = row[j + 1], s2 = row[j + 2], s3 = row[j + 3];
            acc += (g[(size_t)s0 * HID + lane] + g[(size_t)s1 * HID + lane]) +
                   (g[(size_t)s2 * HID + lane] + g[(size_t)s3 * HID + lane]);
        }
        for (; j < len; ++j) acc += g[(size_t)row[j] * HID + lane];
        float h = fmaxf(dinv[node] * acc + bias[lane], 0.0f);
        sH[wv][lane] = h;
    }
    __syncthreads();
    if (node < n) {
        const float* hr = sH[wv];
        float o = 0.0f;
#pragma unroll
        for (int k = 0; k < HID; k += 4) {
            o = fmaf(hr[k + 0], sW[(k + 0) * HID + lane], o);
            o = fmaf(hr[k + 1], sW[(k + 1) * HID + lane], o);
            o = fmaf(hr[k + 2], sW[(k + 2) * HID + lane], o);
            o = fmaf(hr[k + 3], sW[(k + 3) * HID + lane], o);
        }
        gout[(size_t)node * HID + lane] = o * dinv[node];
    }
}
__launch_bounds__(256)
__global__ void k_aggregate_ell(const int* __restrict__ deg, const int* __restrict__ ell,
                                const float* __restrict__ g, float* __restrict__ out,
                                const float* __restrict__ dinv, const float* __restrict__ b,
                                int n) {
    int node = (int)(((long)blockIdx.x * 256 + threadIdx.x) >> 6);
    int lane = threadIdx.x & 63;
    if (node >= n) return;
    int dg = deg[node];
    int len = dg < ELLW ? dg : ELLW;
    const int* row = ell + (size_t)node * ELLW;
    float acc = g[(size_t)node * HID + lane];
    int j = 0;
    for (; j + 4 <= len; j += 4) {
        int s0 = row[j], s1 = row[j + 1], s2 = row[j + 2], s3 = row[j + 3];
        acc += (g[(size_t)s0 * HID + lane] + g[(size_t)s1 * HID + lane]) +
               (g[(size_t)s2 * HID + lane] + g[(size_t)s3 * HID + lane]);
    }
    for (; j < len; ++j) acc += g[(size_t)row[j] * HID + lane];
    out[(size_t)node * HID + lane] = dinv[node] * acc + b[lane];
}
__launch_bounds__(256)
__global__ void k_score_f32(const int* __restrict__ ls, const int* __restrict__ ld,
                            const float* __restrict__ h, float* __restrict__ out, int EL) {
    long t = (long)blockIdx.x * 256 + threadIdx.x;
    long e = t >> 4;
    if (e >= EL) return;
    int q = (int)(t & 15);
    int s = ls[e];
    int d = ld[e];
    float4 a  = *(const float4*)(h + (size_t)s * HID + q * 4);
    float4 bb = *(const float4*)(h + (size_t)d * HID + q * 4);
    float p = a.x * bb.x + a.y * bb.y + a.z * bb.z + a.w * bb.w;
    p += __shfl_xor(p, 1);
    p += __shfl_xor(p, 2);
    p += __shfl_xor(p, 4);
    p += __shfl_xor(p, 8);
    if (q == 0) out[e] = 1.0f / (1.0f + __expf(-p));
}

static inline size_t alignup(size_t v) { return (v + 255) & ~(size_t)255; }

extern "C" void kernel_launch(void* const* d_in, const int* in_sizes, int n_in,
                              void* d_out, int out_size, void* d_ws, size_t ws_size,
                              hipStream_t stream) {
    const float* x  = (const float*)d_in[0];
    const float* W1 = (const float*)d_in[1];
    const float* b1 = (const float*)d_in[2];
    const float* W2 = (const float*)d_in[3];
    const float* b2 = (const float*)d_in[4];
    const float* W3 = (const float*)d_in[5];
    const float* b3 = (const float*)d_in[6];
    const int* ei  = (const int*)d_in[7];
    const int* eli = (const int*)d_in[8];

    const int n  = in_sizes[0] / 128;
    const int E  = in_sizes[7] / 2;
    const int EL = in_sizes[8] / 2;
    float* out = (float*)d_out;

    const int* esrc = ei;
    const int* edst = ei + E;

    const long nh = (long)n * HID;
    const int nBlk  = (n + 255) / 256;
    const int eBlk  = (E + 255) / 256;
    const int aBlk  = (n + 7) / 8;
    const int nb = (n + BN - 1) >> BSH;
    const int chunk = (E + PB - 1) / PB;

    // -------- workspace layout (bf16 main path) --------
    size_t o = 0;
    char* ws = (char*)d_ws;
    int*   table  = (int*)(ws + o); o += alignup((size_t)MAXNB * PB * 4);
    int*   rowsum = (int*)(ws + o); o += alignup((size_t)MAXNB * 4);
    int*   deg    = (int*)(ws + o); o += alignup((size_t)n * 4);
    float* dinv   = (float*)(ws + o); o += alignup((size_t)n * 4);
    int*   ell    = (int*)(ws + o); o += alignup((size_t)n * ELLW * 4);
    bfraw* bufA   = (bfraw*)(ws + o); o += alignup((nh + HID) * 2);   // +1 zero pad row
    bfraw* bufB   = (bfraw*)(ws + o); o += alignup((nh + HID) * 2);
    const size_t need_main = o;
    int* part = (int*)bufA;  // E ints <= (nh+HID)*2 bytes; dead before gemm writes bufA

    if (n <= (1 << SRCBITS) && nb <= MAXNB && (long)E * 2 <= nh + HID && ws_size >= need_main) {
        // ---- build: contention-free two-pass partition + per-bucket ELL ----
        k_hist<<<PB, 256, 0, stream>>>(edst, table, E, nb, chunk);
        k_scanA<<<nb, PB, 0, stream>>>(table, rowsum);
        k_scanB<<<1, PB, 0, stream>>>(rowsum, nb);
        k_pscatter<<<PB, 256, 0, stream>>>(esrc, edst, table, rowsum, part, E, nb, chunk);
        k_bell<<<nb, 256, 0, stream>>>(part, table, rowsum, ell, deg, dinv, E, nb, n);
        k_zero_padrow<<<1, 64, 0, stream>>>(bufA, bufB, nh);

        // ---- layers (bf16 staged features, fp32 math) ----
        k_gemm_bf<128><<<(n + 63) / 64, 256, 0, stream>>>(x, W1, dinv, bufA, n);     // g1 (kills part)
        k_aggb<true ><<<aBlk, 256, 0, stream>>>(deg, ell, bufA, dinv, b1, W2, bufB, n); // g2
        k_aggb<true ><<<aBlk, 256, 0, stream>>>(deg, ell, bufB, dinv, b2, W3, bufA, n); // g3
        k_aggb<false><<<aBlk, 256, 0, stream>>>(deg, ell, bufA, dinv, b3, (const float*)0, bufB, n); // h3

        k_score_bf<<<(EL + 31) / 32, 256, 0, stream>>>(eli, eli + EL, bufB, out, EL);
    } else {
        // -------- fallback: proven r3 fp32 single-pass ELL path --------
        size_t o2 = 0;
        int*   cur   = (int*)(ws + o2);   o2 += alignup((size_t)n * 4);
        float* dinv2 = (float*)(ws + o2); o2 += alignup((size_t)n * 4);
        int*   ell2  = (int*)(ws + o2);   o2 += alignup((size_t)n * ELLW * 4);
        float* fA    = (float*)(ws + o2); o2 += alignup(nh * 4);
        float* fB    = (float*)(ws + o2); o2 += alignup(nh * 4);
        const int aBlk4 = (n + 3) / 4;

        k_zero_int<<<nBlk, 256, 0, stream>>>(cur, n);
        k_ell_fill<<<eBlk, 256, 0, stream>>>(esrc, edst, cur, ell2, E);
        k_dinv_from_deg<<<nBlk, 256, 0, stream>>>(cur, dinv2, n);

        k_gemm_f32<128><<<(n + 31) / 32, 256, 0, stream>>>(x, W1, dinv2, fA, n);
        k_agg_gemm<<<aBlk4, 256, 0, stream>>>(cur, ell2, fA, dinv2, b1, W2, fB, n);
        k_agg_gemm<<<aBlk4, 256, 0, stream>>>(cur, ell2, fB, dinv2, b2, W3, fA, n);
        k_aggregate_ell<<<aBlk4, 256, 0, stream>>>(cur, ell2, fA, fB, dinv2, b3, n);

        k_score_f32<<<(int)(((long)EL * 16 + 255) / 256), 256, 0, stream>>>(eli, eli + EL, fA, out, EL);
    }
}

// Round 13
// 304.885 us; speedup vs baseline: 1.1062x; 1.1062x over previous
//
#include <hip/hip_runtime.h>
#include <math.h>

#define HID 64
#define BSH 8                      // 256 nodes per bucket
#define BN 256
#define SRCBITS 17
#define SRCMASK ((1 << SRCBITS) - 1)
#define PB 512                     // partition chunks
#define MAXNB 512                  // max buckets (n <= 131072)
#define ELLW 96
#define ROWB 7                     // log2 bytes per bf16 row (64*2)

typedef unsigned short bfraw;      // raw bf16 storage
typedef float f32x2 __attribute__((ext_vector_type(2)));
typedef __bf16 bf16x2_t __attribute__((ext_vector_type(2)));

__device__ __forceinline__ float bf_lo(unsigned u) { return __uint_as_float(u << 16); }
__device__ __forceinline__ float bf_hi(unsigned u) { return __uint_as_float(u & 0xffff0000u); }
__device__ __forceinline__ unsigned short f2bf(float f) {
    unsigned u = __float_as_uint(f);
    u += 0x7fffu + ((u >> 16) & 1u);   // round-to-nearest-even (finite values)
    return (unsigned short)(u >> 16);
}
__device__ __forceinline__ unsigned pack2(float a, float b) {
    return (unsigned)f2bf(a) | ((unsigned)f2bf(b) << 16);
}
// packed bf16 pair -> f32 pair
__device__ __forceinline__ f32x2 bf2f2(unsigned u) {
#if __has_builtin(__builtin_amdgcn_cvt_scalef32_pk_f32_bf16)
    return __builtin_amdgcn_cvt_scalef32_pk_f32_bf16(__builtin_bit_cast(bf16x2_t, u), 1.0f);
#else
    f32x2 r;
    r.x = bf_lo(u);
    r.y = bf_hi(u);
    return r;
#endif
}

// acc[c] += sum_j xv[j] * wj[c]
__device__ __forceinline__ void fma4x4(float4& acc, const float4 xv,
                                       const float4 w0, const float4 w1,
                                       const float4 w2, const float4 w3) {
    acc.x = fmaf(xv.x, w0.x, acc.x); acc.y = fmaf(xv.x, w0.y, acc.y);
    acc.z = fmaf(xv.x, w0.z, acc.z); acc.w = fmaf(xv.x, w0.w, acc.w);
    acc.x = fmaf(xv.y, w1.x, acc.x); acc.y = fmaf(xv.y, w1.y, acc.y);
    acc.z = fmaf(xv.y, w1.z, acc.z); acc.w = fmaf(xv.y, w1.w, acc.w);
    acc.x = fmaf(xv.z, w2.x, acc.x); acc.y = fmaf(xv.z, w2.y, acc.y);
    acc.z = fmaf(xv.z, w2.z, acc.z); acc.w = fmaf(xv.z, w2.w, acc.w);
    acc.x = fmaf(xv.w, w3.x, acc.x); acc.y = fmaf(xv.w, w3.y, acc.y);
    acc.z = fmaf(xv.w, w3.z, acc.z); acc.w = fmaf(xv.w, w3.w, acc.w);
}

// ================= small utility =================
__global__ void k_zero_int(int* __restrict__ p, int n) {
    int i = blockIdx.x * blockDim.x + threadIdx.x;
    if (i < n) p[i] = 0;
}

__global__ void k_zero_padrow(bfraw* __restrict__ a, bfraw* __restrict__ b, long off) {
    int t = threadIdx.x;
    if (t < HID) { a[off + t] = 0; b[off + t] = 0; }
}

// ================= P1: per-chunk bucket histogram =================
__global__ void k_hist(const int* __restrict__ dst, int* __restrict__ table,
                       int E, int nb, int chunk) {
    __shared__ int lh[MAXNB];
    for (int t = threadIdx.x; t < nb; t += 256) lh[t] = 0;
    __syncthreads();
    int beg = blockIdx.x * chunk;
    int end = beg + chunk; if (end > E) end = E;
    for (int e = beg + threadIdx.x; e < end; e += 256)
        atomicAdd(&lh[dst[e] >> BSH], 1);
    __syncthreads();
    for (int t = threadIdx.x; t < nb; t += 256)
        table[t * PB + blockIdx.x] = lh[t];
}

// ================= P2a: per-bucket exclusive scan across chunks =================
__global__ void k_scanA(int* __restrict__ table, int* __restrict__ rowsum) {
    __shared__ int lds[PB];
    const int bu = blockIdx.x;
    const int t = threadIdx.x;
    int v = table[bu * PB + t];
    lds[t] = v;
    __syncthreads();
    for (int off = 1; off < PB; off <<= 1) {
        int u = (t >= off) ? lds[t - off] : 0;
        __syncthreads();
        lds[t] += u;
        __syncthreads();
    }
    table[bu * PB + t] = lds[t] - v;
    if (t == PB - 1) rowsum[bu] = lds[t];
}

// ================= P2b: exclusive scan of bucket totals =================
__global__ void k_scanB(int* __restrict__ rowsum, int nb) {
    __shared__ int lds[PB];
    const int t = threadIdx.x;
    int v = (t < nb) ? rowsum[t] : 0;
    lds[t] = v;
    __syncthreads();
    for (int off = 1; off < PB; off <<= 1) {
        int u = (t >= off) ? lds[t - off] : 0;
        __syncthreads();
        lds[t] += u;
        __syncthreads();
    }
    if (t < nb) rowsum[t] = lds[t] - v;
}

// ================= P3: partition scatter (bucket base folded in) =================
__global__ void k_pscatter(const int* __restrict__ src, const int* __restrict__ dst,
                           const int* __restrict__ excl, const int* __restrict__ rowsum,
                           int* __restrict__ part, int E, int nb, int chunk) {
    __shared__ int cur[MAXNB];
    for (int t = threadIdx.x; t < nb; t += 256)
        cur[t] = excl[t * PB + blockIdx.x] + rowsum[t];
    __syncthreads();
    int beg = blockIdx.x * chunk;
    int end = beg + chunk; if (end > E) end = E;
    for (int e = beg + threadIdx.x; e < end; e += 256) {
        int d = dst[e];
        int bu = d >> BSH;
        int pos = atomicAdd(&cur[bu], 1);
        part[pos] = ((d & (BN - 1)) << SRCBITS) | src[e];
    }
}

// ================= P4: per-bucket ELL fill (BYTE offsets) + degree + dinv + pad-to-8 ==========
__global__ void k_bell(const int* __restrict__ part, const int* __restrict__ excl,
                       const int* __restrict__ rowsum,
                       int* __restrict__ ell, int* __restrict__ deg,
                       float* __restrict__ dinv, int E, int nb, int n) {
    __shared__ int cnt[BN];
    int b = blockIdx.x;
    for (int t = threadIdx.x; t < BN; t += 256) cnt[t] = 0;
    __syncthreads();
    int beg = excl[b * PB] + rowsum[b];
    int end = (b == nb - 1) ? E : excl[(b + 1) * PB] + rowsum[b + 1];
    for (int i = beg + threadIdx.x; i < end; i += 256) {
        int c = part[i];
        int dl = c >> SRCBITS;
        int p = atomicAdd(&cnt[dl], 1);
        if (p < ELLW) ell[(size_t)((b << BSH) + dl) * ELLW + p] = (c & SRCMASK) << ROWB;
    }
    __syncthreads();
    for (int t = threadIdx.x; t < BN; t += 256) {
        int node = (b << BSH) + t;
        if (node < n) {
            int dgv = cnt[t];
            int len = dgv < ELLW ? dgv : ELLW;
            int len8 = (len + 7) & ~7;      // ELLW%8==0 so len8<=ELLW
            int* r = ell + (size_t)node * ELLW;
            for (int p = len; p < len8; ++p) r[p] = n << ROWB;   // pad -> zero row
            deg[node] = dgv;
            dinv[node] = rsqrtf((float)(dgv + 1));
        }
    }
}

// ================= GEMM + dinv scale -> bf16 (b128 W reads, 4-row x 4-ch register tile) ========
template<int K>
__launch_bounds__(256)
__global__ void k_gemm_bf(const float* __restrict__ x, const float* __restrict__ W,
                          const float* __restrict__ dinv, bfraw* __restrict__ g, int n) {
    __shared__ float sW[K * HID];
    for (int t = threadIdx.x; t < K * HID / 4; t += 256)
        ((float4*)sW)[t] = ((const float4*)W)[t];
    __syncthreads();
    const int wv = threadIdx.x >> 6;
    const int lane = threadIdx.x & 63;
    const int cq = lane & 15;
    const int rq = lane >> 4;
    const int base = blockIdx.x * 64 + wv * 16 + rq * 4;
    if (base >= n) return;
    if (base + 3 < n) {
        const float* xr = x + (size_t)base * K;
        float4 a0 = {0,0,0,0}, a1 = {0,0,0,0}, a2 = {0,0,0,0}, a3 = {0,0,0,0};
#pragma unroll 2
        for (int k = 0; k < K; k += 4) {
            float4 x0 = *(const float4*)(xr + k);
            float4 x1 = *(const float4*)(xr + K + k);
            float4 x2 = *(const float4*)(xr + 2 * K + k);
            float4 x3 = *(const float4*)(xr + 3 * K + k);
            const float* wp = sW + k * HID + cq * 4;
            float4 w0 = *(const float4*)(wp);
            float4 w1 = *(const float4*)(wp + HID);
            float4 w2 = *(const float4*)(wp + 2 * HID);
            float4 w3 = *(const float4*)(wp + 3 * HID);
            fma4x4(a0, x0, w0, w1, w2, w3);
            fma4x4(a1, x1, w0, w1, w2, w3);
            fma4x4(a2, x2, w0, w1, w2, w3);
            fma4x4(a3, x3, w0, w1, w2, w3);
        }
        float d0 = dinv[base], d1 = dinv[base + 1], d2 = dinv[base + 2], d3 = dinv[base + 3];
        uint2 o;
        o.x = pack2(a0.x * d0, a0.y * d0); o.y = pack2(a0.z * d0, a0.w * d0);
        *(uint2*)(g + (size_t)(base + 0) * HID + cq * 4) = o;
        o.x = pack2(a1.x * d1, a1.y * d1); o.y = pack2(a1.z * d1, a1.w * d1);
        *(uint2*)(g + (size_t)(base + 1) * HID + cq * 4) = o;
        o.x = pack2(a2.x * d2, a2.y * d2); o.y = pack2(a2.z * d2, a2.w * d2);
        *(uint2*)(g + (size_t)(base + 2) * HID + cq * 4) = o;
        o.x = pack2(a3.x * d3, a3.y * d3); o.y = pack2(a3.z * d3, a3.w * d3);
        *(uint2*)(g + (size_t)(base + 3) * HID + cq * 4) = o;
    } else {
        for (int r = 0; r < 4; ++r) {
            int row = base + r;
            if (row >= n) break;
            const float* xp = x + (size_t)row * K;
            float4 acc = {0,0,0,0};
            for (int k = 0; k < K; k += 4) {
                float4 xv = *(const float4*)(xp + k);
                const float* wp = sW + k * HID + cq * 4;
                float4 w0 = *(const float4*)(wp);
                float4 w1 = *(const float4*)(wp + HID);
                float4 w2 = *(const float4*)(wp + 2 * HID);
                float4 w3 = *(const float4*)(wp + 3 * HID);
                fma4x4(acc, xv, w0, w1, w2, w3);
            }
            float di = dinv[row];
            uint2 o;
            o.x = pack2(acc.x * di, acc.y * di); o.y = pack2(acc.z * di, acc.w * di);
            *(uint2*)(g + (size_t)row * HID + cq * 4) = o;
        }
    }
}

// ================= bf16 aggregation (proven r11 form): 2 nodes/wave, 4 loads in flight ========
// lane bits: [5]=node half, [4:3]=edge group (4/node), [2:0]=channel octet.
template<bool FUSE>
__launch_bounds__(256)
__global__ void k_aggb(const int* __restrict__ deg, const int* __restrict__ ell,
                       const bfraw* __restrict__ g, const float* __restrict__ dinv,
                       const float* __restrict__ bias, const float* __restrict__ Wn,
                       bfraw* __restrict__ outp, int n) {
    __shared__ __align__(16) float sW[FUSE ? HID * HID : 4];
    __shared__ __align__(16) float sH[8][HID];
    if (FUSE) {
        for (int t = threadIdx.x; t < HID * HID / 4; t += 256)
            ((float4*)sW)[t] = ((const float4*)Wn)[t];
    }
    const int wv = threadIdx.x >> 6;
    const int lane = threadIdx.x & 63;
    const int half = lane >> 5;
    const int grp4 = (lane >> 3) & 3;
    const int cq = lane & 7;
    const int cqb = cq * 16;             // byte offset within row
    const int nodeSlot = wv * 2 + half;
    const int node = blockIdx.x * 8 + nodeSlot;
    const char* gb = (const char*)g;
    f32x2 a01 = {0, 0}, a23 = {0, 0}, a45 = {0, 0}, a67 = {0, 0};
    if (node < n) {
        int dg = deg[node];
        int len = dg < ELLW ? dg : ELLW;
        int len8 = (len + 7) & ~7;
        const int* row = ell + (size_t)node * ELLW;
        int j = grp4;
        for (; j + 12 < len8; j += 16) {     // 4 loads in flight per lane
            int o0 = row[j], o1 = row[j + 4], o2 = row[j + 8], o3 = row[j + 12];
            const uint4 v0 = *(const uint4*)(gb + o0 + cqb);
            const uint4 v1 = *(const uint4*)(gb + o1 + cqb);
            const uint4 v2 = *(const uint4*)(gb + o2 + cqb);
            const uint4 v3 = *(const uint4*)(gb + o3 + cqb);
            a01 += (bf2f2(v0.x) + bf2f2(v1.x)) + (bf2f2(v2.x) + bf2f2(v3.x));
            a23 += (bf2f2(v0.y) + bf2f2(v1.y)) + (bf2f2(v2.y) + bf2f2(v3.y));
            a45 += (bf2f2(v0.z) + bf2f2(v1.z)) + (bf2f2(v2.z) + bf2f2(v3.z));
            a67 += (bf2f2(v0.w) + bf2f2(v1.w)) + (bf2f2(v2.w) + bf2f2(v3.w));
        }
        for (; j < len8; j += 4) {
            int o0 = row[j];
            const uint4 v0 = *(const uint4*)(gb + o0 + cqb);
            a01 += bf2f2(v0.x);
            a23 += bf2f2(v0.y);
            a45 += bf2f2(v0.z);
            a67 += bf2f2(v0.w);
        }
    }
    // reduce across 4 groups within each 32-lane half (bit5 never crossed)
    a01.x += __shfl_xor(a01.x, 8);  a01.y += __shfl_xor(a01.y, 8);
    a23.x += __shfl_xor(a23.x, 8);  a23.y += __shfl_xor(a23.y, 8);
    a45.x += __shfl_xor(a45.x, 8);  a45.y += __shfl_xor(a45.y, 8);
    a67.x += __shfl_xor(a67.x, 8);  a67.y += __shfl_xor(a67.y, 8);
    a01.x += __shfl_xor(a01.x, 16); a01.y += __shfl_xor(a01.y, 16);
    a23.x += __shfl_xor(a23.x, 16); a23.y += __shfl_xor(a23.y, 16);
    a45.x += __shfl_xor(a45.x, 16); a45.y += __shfl_xor(a45.y, 16);
    a67.x += __shfl_xor(a67.x, 16); a67.y += __shfl_xor(a67.y, 16);
    if (node < n && grp4 == 0) {
        const uint4 sv = *(const uint4*)(gb + ((size_t)node << ROWB) + cqb);
        float di = dinv[node];
        const float4 bv0 = *(const float4*)(bias + cq * 8);
        const float4 bv1 = *(const float4*)(bias + cq * 8 + 4);
        f32x2 se0 = bf2f2(sv.x), se1 = bf2f2(sv.y), se2 = bf2f2(sv.z), se3 = bf2f2(sv.w);
        float h0 = di * (a01.x + se0.x) + bv0.x;
        float h1 = di * (a01.y + se0.y) + bv0.y;
        float h2 = di * (a23.x + se1.x) + bv0.z;
        float h3 = di * (a23.y + se1.y) + bv0.w;
        float h4 = di * (a45.x + se2.x) + bv1.x;
        float h5 = di * (a45.y + se2.y) + bv1.y;
        float h6 = di * (a67.x + se3.x) + bv1.z;
        float h7 = di * (a67.y + se3.y) + bv1.w;
        if (!FUSE) {
            uint4 o;
            o.x = pack2(h0, h1); o.y = pack2(h2, h3);
            o.z = pack2(h4, h5); o.w = pack2(h6, h7);
            *(uint4*)(outp + (size_t)node * HID + cq * 8) = o;
        } else {
            h0 = fmaxf(h0, 0.0f); h1 = fmaxf(h1, 0.0f); h2 = fmaxf(h2, 0.0f); h3 = fmaxf(h3, 0.0f);
            h4 = fmaxf(h4, 0.0f); h5 = fmaxf(h5, 0.0f); h6 = fmaxf(h6, 0.0f); h7 = fmaxf(h7, 0.0f);
            *(float4*)(&sH[nodeSlot][cq * 8])     = make_float4(h0, h1, h2, h3);
            *(float4*)(&sH[nodeSlot][cq * 8 + 4]) = make_float4(h4, h5, h6, h7);
        }
    }
    if (FUSE) {
        __syncthreads();   // covers sW staging + sH visibility
        const int c4 = lane & 15;
        const int kh = (lane >> 4) & 1;
        float4 acc = {0, 0, 0, 0};
        if (node < n) {
            const float* hr = sH[nodeSlot];
#pragma unroll
            for (int kk = 0; kk < 32; kk += 4) {
                int k = kh * 32 + kk;
                float4 hv = *(const float4*)(hr + k);
                const float* wp = sW + k * HID + c4 * 4;
                float4 w0 = *(const float4*)(wp);
                float4 w1 = *(const float4*)(wp + HID);
                float4 w2 = *(const float4*)(wp + 2 * HID);
                float4 w3 = *(const float4*)(wp + 3 * HID);
                fma4x4(acc, hv, w0, w1, w2, w3);
            }
        }
        acc.x += __shfl_xor(acc.x, 16); acc.y += __shfl_xor(acc.y, 16);
        acc.z += __shfl_xor(acc.z, 16); acc.w += __shfl_xor(acc.w, 16);
        if (node < n && kh == 0) {
            float di = dinv[node];
            uint2 o;
            o.x = pack2(acc.x * di, acc.y * di);
            o.y = pack2(acc.z * di, acc.w * di);
            *(uint2*)(outp + (size_t)node * HID + c4 * 4) = o;
        }
    }
}

// ================= link scores from bf16 h3: 8 lanes/edge =================
__launch_bounds__(256)
__global__ void k_score_bf(const int* __restrict__ ls, const int* __restrict__ ld,
                           const bfraw* __restrict__ h, float* __restrict__ out, int EL) {
    const int wv = threadIdx.x >> 6;
    const int lane = threadIdx.x & 63;
    const int grp = lane >> 3;
    const int cq = lane & 7;
    long e = (long)blockIdx.x * 32 + wv * 8 + grp;
    if (e >= EL) return;   // group-uniform
    int s = ls[e];
    int d = ld[e];
    const uint4 va = *(const uint4*)(h + (size_t)s * HID + cq * 8);
    const uint4 vb = *(const uint4*)(h + (size_t)d * HID + cq * 8);
    f32x2 a0 = bf2f2(va.x), b0 = bf2f2(vb.x);
    f32x2 a1 = bf2f2(va.y), b1 = bf2f2(vb.y);
    f32x2 a2 = bf2f2(va.z), b2 = bf2f2(vb.z);
    f32x2 a3 = bf2f2(va.w), b3 = bf2f2(vb.w);
    float p = a0.x * b0.x + a0.y * b0.y + a1.x * b1.x + a1.y * b1.y
            + a2.x * b2.x + a2.y * b2.y + a3.x * b3.x + a3.y * b3.y;
    p += __shfl_xor(p, 1);
    p += __shfl_xor(p, 2);
    p += __shfl_xor(p, 4);
    if (cq == 0) out[e] = 1.0f / (1.0f + __expf(-p));
}

// ================= fallback: proven r3 fp32 kernels (index-based ELL) =================
__global__ void k_ell_fill(const int* __restrict__ src, const int* __restrict__ dst,
                           int* __restrict__ cur, int* __restrict__ ell, int E) {
    int e = blockIdx.x * blockDim.x + threadIdx.x;
    if (e < E) {
        int d = dst[e];
        int p = atomicAdd(&cur[d], 1);
        if (p < ELLW) ell[(size_t)d * ELLW + p] = src[e];
    }
}
__global__ void k_dinv_from_deg(const int* __restrict__ deg, float* __restrict__ dinv, int n) {
    int i = blockIdx.x * blockDim.x + threadIdx.x;
    if (i < n) dinv[i] = rsqrtf((float)(deg[i] + 1));
}
template<int K>
__launch_bounds__(256)
__global__ void k_gemm_f32(const float* __restrict__ x, const float* __restrict__ W,
                           const float* __restrict__ dinv, float* __restrict__ g, int n) {
    __shared__ float sW[K * HID];
    for (int t = threadIdx.x; t < K * HID; t += 256) sW[t] = W[t];
    __syncthreads();
    const int lane = threadIdx.x & 63;
    const int rowInBlk = threadIdx.x >> 6;
    const int ROWS = 32;
    const int base = blockIdx.x * ROWS;
    for (int r = rowInBlk; r < ROWS; r += 4) {
        int i = base + r;
        if (i >= n) return;
        const float* xr = x + (size_t)i * K;
        float acc = 0.0f;
#pragma unroll
        for (int k = 0; k < K; k += 4) {
            float4 xv = *(const float4*)(xr + k);
            acc = fmaf(xv.x, sW[(k + 0) * HID + lane], acc);
            acc = fmaf(xv.y, sW[(k + 1) * HID + lane], acc);
            acc = fmaf(xv.z, sW[(k + 2) * HID + lane], acc);
            acc = fmaf(xv.w, sW[(k + 3) * HID + lane], acc);
        }
        g[(size_t)i * HID + lane] = acc * dinv[i];
    }
}
__launch_bounds__(256)
__global__ void k_agg_gemm(const int* __restrict__ deg, const int* __restrict__ ell,
                           const float* __restrict__ g, const float* __restrict__ dinv,
                           const float* __restrict__ bias, const float* __restrict__ Wn,
                           float* __restrict__ gout, int n) {
    __shared__ float sW[HID * HID];
    __shared__ float sH[4][HID];
    for (int t = threadIdx.x; t < HID * HID; t += 256) sW[t] = Wn[t];
    const int wv = threadIdx.x >> 6;
    const int lane = threadIdx.x & 63;
    const int node = blockIdx.x * 4 + wv;
    if (node < n) {
        int dg = deg[node];
        int len = dg < ELLW ? dg : ELLW;
        const int* row = ell + (size_t)node * ELLW;
        float acc = g[(size_t)node * HID + lane];
        int j = 0;
        for (; j + 4 <= len; j += 4) {
            int s0 = row[j], s1 = row[j + 1], s2 = row[j + 2], s3 = row[j + 3];
            acc += (g[(size_t)s0 * HID + lane] + g[(size_t)s1 * HID + lane]) +
                   (g[(size_t)s2 * HID + lane] + g[(size_t)s3 * HID + lane]);
        }
        for (; j < len; ++j) acc += g[(size_t)row[j] * HID + lane];
        float h = fmaxf(dinv[node] * acc + bias[lane], 0.0f);
        sH[wv][lane] = h;
    }
    __syncthreads();
    if (node < n) {
        const float* hr = sH[wv];
        float o = 0.0f;
#pragma unroll
        for (int k = 0; k < HID; k += 4) {
            o = fmaf(hr[k + 0], sW[(k + 0) * HID + lane], o);
            o = fmaf(hr[k + 1], sW[(k + 1) * HID + lane], o);
            o = fmaf(hr[k + 2], sW[(k + 2) * HID + lane], o);
            o = fmaf(hr[k + 3], sW[(k + 3) * HID + lane], o);
        }
        gout[(size_t)node * HID + lane] = o * dinv[node];
    }
}
__launch_bounds__(256)
__global__ void k_aggregate_ell(const int* __restrict__ deg, const int* __restrict__ ell,
                                const float* __restrict__ g, float* __restrict__ out,
                                const float* __restrict__ dinv, const float* __restrict__ b,
                                int n) {
    int node = (int)(((long)blockIdx.x * 256 + threadIdx.x) >> 6);
    int lane = threadIdx.x & 63;
    if (node >= n) return;
    int dg = deg[node];
    int len = dg < ELLW ? dg : ELLW;
    const int* row = ell + (size_t)node * ELLW;
    float acc = g[(size_t)node * HID + lane];
    int j = 0;
    for (; j + 4 <= len; j += 4) {
        int s0 = row[j], s1 = row[j + 1], s2 = row[j + 2], s3 = row[j + 3];
        acc += (g[(size_t)s0 * HID + lane] + g[(size_t)s1 * HID + lane]) +
               (g[(size_t)s2 * HID + lane] + g[(size_t)s3 * HID + lane]);
    }
    for (; j < len; ++j) acc += g[(size_t)row[j] * HID + lane];
    out[(size_t)node * HID + lane] = dinv[node] * acc + b[lane];
}
__launch_bounds__(256)
__global__ void k_score_f32(const int* __restrict__ ls, const int* __restrict__ ld,
                            const float* __restrict__ h, float* __restrict__ out, int EL) {
    long t = (long)blockIdx.x * 256 + threadIdx.x;
    long e = t >> 4;
    if (e >= EL) return;
    int q = (int)(t & 15);
    int s = ls[e];
    int d = ld[e];
    float4 a  = *(const float4*)(h + (size_t)s * HID + q * 4);
    float4 bb = *(const float4*)(h + (size_t)d * HID + q * 4);
    float p = a.x * bb.x + a.y * bb.y + a.z * bb.z + a.w * bb.w;
    p += __shfl_xor(p, 1);
    p += __shfl_xor(p, 2);
    p += __shfl_xor(p, 4);
    p += __shfl_xor(p, 8);
    if (q == 0) out[e] = 1.0f / (1.0f + __expf(-p));
}

static inline size_t alignup(size_t v) { return (v + 255) & ~(size_t)255; }

extern "C" void kernel_launch(void* const* d_in, const int* in_sizes, int n_in,
                              void* d_out, int out_size, void* d_ws, size_t ws_size,
                              hipStream_t stream) {
    const float* x  = (const float*)d_in[0];
    const float* W1 = (const float*)d_in[1];
    const float* b1 = (const float*)d_in[2];
    const float* W2 = (const float*)d_in[3];
    const float* b2 = (const float*)d_in[4];
    const float* W3 = (const float*)d_in[5];
    const float* b3 = (const float*)d_in[6];
    const int* ei  = (const int*)d_in[7];
    const int* eli = (const int*)d_in[8];

    const int n  = in_sizes[0] / 128;
    const int E  = in_sizes[7] / 2;
    const int EL = in_sizes[8] / 2;
    float* out = (float*)d_out;

    const int* esrc = ei;
    const int* edst = ei + E;

    const long nh = (long)n * HID;
    const int nBlk  = (n + 255) / 256;
    const int eBlk  = (E + 255) / 256;
    const int aBlk  = (n + 7) / 8;
    const int nb = (n + BN - 1) >> BSH;
    const int chunk = (E + PB - 1) / PB;

    // -------- workspace layout (bf16 main path) --------
    size_t o = 0;
    char* ws = (char*)d_ws;
    int*   table  = (int*)(ws + o); o += alignup((size_t)MAXNB * PB * 4);
    int*   rowsum = (int*)(ws + o); o += alignup((size_t)MAXNB * 4);
    int*   deg    = (int*)(ws + o); o += alignup((size_t)n * 4);
    float* dinv   = (float*)(ws + o); o += alignup((size_t)n * 4);
    int*   ell    = (int*)(ws + o); o += alignup((size_t)n * ELLW * 4);
    bfraw* bufA   = (bfraw*)(ws + o); o += alignup((nh + HID) * 2);   // +1 zero pad row
    bfraw* bufB   = (bfraw*)(ws + o); o += alignup((nh + HID) * 2);
    const size_t need_main = o;
    int* part = (int*)bufA;  // E ints <= (nh+HID)*2 bytes; dead before gemm writes bufA

    if (n <= (1 << SRCBITS) && nb <= MAXNB && (long)E * 2 <= nh + HID && ws_size >= need_main) {
        // ---- build: contention-free two-pass partition + per-bucket ELL ----
        k_hist<<<PB, 256, 0, stream>>>(edst, table, E, nb, chunk);
        k_scanA<<<nb, PB, 0, stream>>>(table, rowsum);
        k_scanB<<<1, PB, 0, stream>>>(rowsum, nb);
        k_pscatter<<<PB, 256, 0, stream>>>(esrc, edst, table, rowsum, part, E, nb, chunk);
        k_bell<<<nb, 256, 0, stream>>>(part, table, rowsum, ell, deg, dinv, E, nb, n);
        k_zero_padrow<<<1, 64, 0, stream>>>(bufA, bufB, nh);

        // ---- layers (bf16 staged features, fp32 math) ----
        k_gemm_bf<128><<<(n + 63) / 64, 256, 0, stream>>>(x, W1, dinv, bufA, n);     // g1 (kills part)
        k_aggb<true ><<<aBlk, 256, 0, stream>>>(deg, ell, bufA, dinv, b1, W2, bufB, n); // g2
        k_aggb<true ><<<aBlk, 256, 0, stream>>>(deg, ell, bufB, dinv, b2, W3, bufA, n); // g3
        k_aggb<false><<<aBlk, 256, 0, stream>>>(deg, ell, bufA, dinv, b3, (const float*)0, bufB, n); // h3

        k_score_bf<<<(EL + 31) / 32, 256, 0, stream>>>(eli, eli + EL, bufB, out, EL);
    } else {
        // -------- fallback: proven r3 fp32 single-pass ELL path --------
        size_t o2 = 0;
        int*   cur   = (int*)(ws + o2);   o2 += alignup((size_t)n * 4);
        float* dinv2 = (float*)(ws + o2); o2 += alignup((size_t)n * 4);
        int*   ell2  = (int*)(ws + o2);   o2 += alignup((size_t)n * ELLW * 4);
        float* fA    = (float*)(ws + o2); o2 += alignup(nh * 4);
        float* fB    = (float*)(ws + o2); o2 += alignup(nh * 4);
        const int aBlk4 = (n + 3) / 4;

        k_zero_int<<<nBlk, 256, 0, stream>>>(cur, n);
        k_ell_fill<<<eBlk, 256, 0, stream>>>(esrc, edst, cur, ell2, E);
        k_dinv_from_deg<<<nBlk, 256, 0, stream>>>(cur, dinv2, n);

        k_gemm_f32<128><<<(n + 31) / 32, 256, 0, stream>>>(x, W1, dinv2, fA, n);
        k_agg_gemm<<<aBlk4, 256, 0, stream>>>(cur, ell2, fA, dinv2, b1, W2, fB, n);
        k_agg_gemm<<<aBlk4, 256, 0, stream>>>(cur, ell2, fB, dinv2, b2, W3, fA, n);
        k_aggregate_ell<<<aBlk4, 256, 0, stream>>>(cur, ell2, fA, fB, dinv2, b3, n);

        k_score_f32<<<(int)(((long)EL * 16 + 255) / 256), 256, 0, stream>>>(eli, eli + EL, fA, out, EL);
    }
}